// Round 20
// baseline (359.243 us; speedup 1.0000x reference)
//
#include <hip/hip_runtime.h>
#include <hip/hip_bf16.h>

#define B_    4
#define C_    256
#define H_    128
#define W_    128
#define NW_   256     // number of windows (B*8*8)
#define N_    256     // tokens per window
#define DA_   64
#define MID_  1024
#define SCALE_ 0.125f

typedef __attribute__((ext_vector_type(8))) __bf16 frag8;
typedef __attribute__((ext_vector_type(4))) float  f32x4;
typedef __attribute__((ext_vector_type(4))) unsigned int u32x4;

#define MFMA(a, b, c) __builtin_amdgcn_mfma_f32_16x16x32_bf16(a, b, c, 0, 0, 0)

__device__ __forceinline__ unsigned short f2bf(float x) {
    union { float f; unsigned u; } v; v.f = x;
    unsigned r = v.u + 0x7FFFu + ((v.u >> 16) & 1u);
    return (unsigned short)(r >> 16);
}
__device__ __forceinline__ float bf2f(unsigned short h) {
    union { unsigned u; float f; } v; v.u = ((unsigned)h) << 16;
    return v.f;
}
__device__ __forceinline__ frag8 loadf8(const unsigned short* p) {
    return *reinterpret_cast<const frag8*>(p);
}

// ---------------- weight prep: fold scales, cast to bf16 ----------------
__global__ void k_wprep(const float* __restrict__ qw, const float* __restrict__ qs,
                        const float* __restrict__ kw, const float* __restrict__ ks,
                        const float* __restrict__ vgw, const float* __restrict__ vgs,
                        const float* __restrict__ pw, const float* __restrict__ ps,
                        unsigned short* __restrict__ wvg,
                        unsigned short* __restrict__ wqk,
                        unsigned short* __restrict__ wp) {
    int i = blockIdx.x * 256 + threadIdx.x;
    if (i < 2048 * 256) {
        int r = i >> 8;
        wvg[i] = f2bf(vgw[i] * vgs[r]);
        return;
    }
    int j = i - 2048 * 256;
    if (j < 128 * 256) {
        int r = j >> 8, c = j & 255;
        float v = (r < 64) ? qw[r * 256 + c] * qs[r] * SCALE_
                           : kw[(r - 64) * 256 + c] * ks[r - 64];
        wqk[j] = f2bf(v);
        return;
    }
    int m = j - 128 * 256;
    if (m < 256 * 1024) {
        int o = m >> 10;
        wp[m] = f2bf(pw[m] * ps[o]);
    }
}

// ---------------- pack: x[B,C,H,W] -> xfT[win][n][c] bf16 ----------------
__global__ void k_pack(const float* __restrict__ x, unsigned short* __restrict__ xfT) {
    __shared__ unsigned short tile[64][258];
    int wdw = blockIdx.x >> 2, cq = blockIdx.x & 3;
    int b = wdw >> 6, wh = (wdw >> 3) & 7, ww = wdw & 7;
    int tid = threadIdx.x;
    int n = tid;
    int h = wh * 16 + (n >> 4), wc = ww * 16 + (n & 15);
    const float* xb = x + ((long)(b * C_ + cq * 64)) * (H_ * W_) + h * W_ + wc;
    #pragma unroll 4
    for (int cl = 0; cl < 64; ++cl)
        tile[cl][n] = f2bf(xb[cl * H_ * W_]);
    __syncthreads();
    unsigned short* dst = xfT + (long)wdw * (N_ * C_) + cq * 64;
    int cl = tid & 63;
    #pragma unroll 4
    for (int it = 0; it < 64; ++it) {
        int nn = it * 4 + (tid >> 6);
        dst[nn * C_ + cl] = tile[cl][nn];
    }
}

// ---------------- attention: q/k conv + softmax(q^T k) -> attn bf16 -------------
// Window split across 2 blocks (grid = 2*NW): each block recomputes stage 1
// (cheap, 16.8 MFLOP/window) and runs ONE stage-2 pass (128 n-rows). The R15
// LDS union (73.7 KB) allows 2 blocks/CU; grid=512 finally uses that residency.
__global__ __launch_bounds__(512, 4) void k_attn(const unsigned short* __restrict__ xfT,
                                                 const unsigned short* __restrict__ wqk,
                                                 const float* __restrict__ qb,
                                                 const float* __restrict__ kb,
                                                 unsigned short* __restrict__ attn) {
    __shared__ __align__(16) char smem[73728];
    unsigned short (*qT)[72] = reinterpret_cast<unsigned short(*)[72]>(smem);
    unsigned short (*kT)[72] = reinterpret_cast<unsigned short(*)[72]>(smem + 36864);
    char* wqlds = smem;   // [128 rows][256 c] bf16, swizzled; aliases qT/kT
    int wdw = blockIdx.x >> 1;
    int pass = blockIdx.x & 1;
    int tid = threadIdx.x, w = tid >> 6, l = tid & 63;
    int l16 = l & 15, lg = l >> 4;
    const unsigned short* xw = xfT + (long)wdw * (N_ * C_);

    {   // cooperative stage wqk -> wqlds; physical byte = row*512 + (bc ^ ((row&7)<<4))
        int srow = tid >> 2;
        int cb = (tid & 3) * 128;
        const u32x4* src = reinterpret_cast<const u32x4*>(wqk + srow * 256 + (tid & 3) * 64);
        int sw = (srow & 7) << 4;
        #pragma unroll
        for (int j = 0; j < 8; ++j)
            *reinterpret_cast<u32x4*>(wqlds + srow * 512 + ((cb + j * 16) ^ sw)) = src[j];
    }
    __syncthreads();

    // stage 1: preact[128 rows][wave's 32 n]; A from LDS, B (xf) from global
    f32x4 acc[8][2];
    #pragma unroll
    for (int a = 0; a < 8; ++a) {
        acc[a][0] = (f32x4){0.f, 0.f, 0.f, 0.f};
        acc[a][1] = (f32x4){0.f, 0.f, 0.f, 0.f};
    }
    for (int kk = 0; kk < 8; ++kk) {
        int c0 = kk * 32 + lg * 8;
        frag8 b0 = loadf8(xw + (32 * w + l16) * 256 + c0);
        frag8 b1 = loadf8(xw + (32 * w + 16 + l16) * 256 + c0);
        int cbyte = c0 * 2;
        #pragma unroll
        for (int rt = 0; rt < 8; ++rt) {
            int row = rt * 16 + l16;
            frag8 af = *reinterpret_cast<const frag8*>(
                wqlds + row * 512 + (cbyte ^ ((row & 7) << 4)));
            acc[rt][0] = MFMA(af, b0, acc[rt][0]);
            acc[rt][1] = MFMA(af, b1, acc[rt][1]);
        }
    }
    __syncthreads();   // all wqlds reads done; qT/kT may now overwrite the region

    #pragma unroll
    for (int rt = 0; rt < 8; ++rt) {
        int rowb = rt * 16 + lg * 4;
        bool isq = rt < 4;
        float b0 = isq ? qb[rowb + 0] * SCALE_ : kb[rowb - 64 + 0];
        float b1 = isq ? qb[rowb + 1] * SCALE_ : kb[rowb - 64 + 1];
        float b2 = isq ? qb[rowb + 2] * SCALE_ : kb[rowb - 64 + 2];
        float b3 = isq ? qb[rowb + 3] * SCALE_ : kb[rowb - 64 + 3];
        #pragma unroll
        for (int ct = 0; ct < 2; ++ct) {
            int col = 32 * w + ct * 16 + l16;
            ushort4 t;
            t.x = f2bf(acc[rt][ct][0] + b0);
            t.y = f2bf(acc[rt][ct][1] + b1);
            t.z = f2bf(acc[rt][ct][2] + b2);
            t.w = f2bf(acc[rt][ct][3] + b3);
            unsigned short* dstp = isq ? &qT[col][rowb] : &kT[col][rowb - 64];
            *reinterpret_cast<ushort4*>(dstp) = t;
        }
    }
    __syncthreads();   // qT/kT ready

    {   // stage 2: this block's single pass (128 n-rows)
        int n0 = pass * 128 + w * 16;
        f32x4 a2[16];
        #pragma unroll
        for (int c = 0; c < 16; ++c) a2[c] = (f32x4){0.f, 0.f, 0.f, 0.f};
        #pragma unroll
        for (int kk = 0; kk < 2; ++kk) {
            int k0 = kk * 32 + lg * 8;
            frag8 af = loadf8(&qT[n0 + l16][k0]);
            #pragma unroll
            for (int ct = 0; ct < 16; ++ct) {
                frag8 bf = loadf8(&kT[ct * 16 + l16][k0]);
                a2[ct] = MFMA(af, bf, a2[ct]);
            }
        }
        #pragma unroll
        for (int r = 0; r < 4; ++r) {
            int n = n0 + lg * 4 + r;
            float mx = -1e30f;
            #pragma unroll
            for (int ct = 0; ct < 16; ++ct) mx = fmaxf(mx, a2[ct][r]);
            #pragma unroll
            for (int d = 1; d < 16; d <<= 1) mx = fmaxf(mx, __shfl_xor(mx, d, 64));
            float p[16], s = 0.f;
            #pragma unroll
            for (int ct = 0; ct < 16; ++ct) { p[ct] = __expf(a2[ct][r] - mx); s += p[ct]; }
            #pragma unroll
            for (int d = 1; d < 16; d <<= 1) s += __shfl_xor(s, d, 64);
            float inv = __builtin_amdgcn_rcpf(s);
            unsigned short* dst = attn + (long)wdw * (N_ * N_) + n * 256 + l16;
            #pragma unroll
            for (int ct = 0; ct < 16; ++ct) dst[ct * 16] = f2bf(p[ct] * inv);
        }
    }
}

// ============== k_vgpv weight-staging helpers (1024-thread variant) ==============
// wlds: linear 32 KB = half weight slab [128 rows][128 c] bf16.
// XOR swizzle: physical_byte(row, bc) = row*256 + (bc ^ ((row&7)<<4)).
// 1024 threads: 8 threads/row x 32 B each.
__device__ __forceinline__ void wstage_load(u32x4 wr[2], const unsigned short* __restrict__ wvg,
                                            int mid0, int h, int tid) {
    int srow = tid >> 3;            // 0..127
    long grow = (srow < 64) ? (long)(mid0 + srow) : (long)(MID_ + mid0 + srow - 64);
    const u32x4* src = reinterpret_cast<const u32x4*>(wvg + grow * 256 + h * 128 + (tid & 7) * 16);
    wr[0] = src[0];
    wr[1] = src[1];
}
__device__ __forceinline__ void wstage_write(const u32x4 wr[2], char* wlds, int tid) {
    int srow = tid >> 3;
    int cb = (tid & 7) * 32;
    int sw = (srow & 7) << 4;
    *reinterpret_cast<u32x4*>(wlds + srow * 256 + (cb ^ sw)) = wr[0];
    *reinterpret_cast<u32x4*>(wlds + srow * 256 + ((cb + 16) ^ sw)) = wr[1];
}
// one c-half of stage A: 4 kk steps, A from LDS (swizzled), B (xf) from global.
// Wave owns 16 n-cols -> single B-frag per kk.
__device__ __forceinline__ void vg_mfma_half(const char* wlds,
                                             const unsigned short* __restrict__ xwA,
                                             int h, int l16, int lg, f32x4 accA[8]) {
    #pragma unroll
    for (int kkl = 0; kkl < 4; ++kkl) {
        int c0 = h * 128 + kkl * 32 + lg * 8;
        frag8 b0 = loadf8(xwA + c0);
        int cbase = kkl * 64 + lg * 16;
        #pragma unroll
        for (int rt = 0; rt < 8; ++rt) {
            int row = rt * 16 + l16;
            frag8 af = *reinterpret_cast<const frag8*>(
                wlds + row * 256 + (cbase ^ ((row & 7) << 4)));
            accA[rt] = MFMA(af, b0, accA[rt]);
        }
    }
}

// ---------------- k_vgpv: vg conv + sigmoid -> PV -> gate -> pvg (global) -------
// R16 exact (best measured passing config: ~220 us).
__global__ __launch_bounds__(1024, 4) void k_vgpv(const unsigned short* __restrict__ xfT,
                                                  const unsigned short* __restrict__ attn,
                                                  const unsigned short* __restrict__ wvg,
                                                  const float* __restrict__ vgb,
                                                  unsigned short* __restrict__ pvg) {
    __shared__ __align__(16) unsigned short vlds[64][264];
    __shared__ __align__(16) char wlds[32768];
    __shared__ float vgb_s[256];     // 2 tiles x (64 v-bias, 64 g-bias)
    int bid = blockIdx.x;
    int lane8 = bid & 7, rr = bid >> 3;
    int sub = rr & 7, winHi = rr >> 3;
    int wdw = winHi * 8 + lane8;
    int mtbase = sub * 2;

    int tid = threadIdx.x, w = tid >> 6, l = tid & 63;   // w: 0..15
    int l16 = l & 15, lg = l >> 4;
    int nb = 16 * w;                                     // wave's 16 n-cols
    const unsigned short* xw = xfT + (long)wdw * (N_ * C_);
    const unsigned short* xwA = xw + (nb + l16) * 256;
    const unsigned short* aw = attn + (long)wdw * (N_ * N_);
    const unsigned short* awA = aw + (nb + l16) * 256;
    unsigned short* pw_out = pvg + (long)wdw * (N_ * MID_);

    if (tid < 256) {   // bias slice: [i*128 + s], s<64 => v, s>=64 => gate
        int i = tid >> 7, s = tid & 127;
        int src = (s < 64) ? ((mtbase + i) * 64 + s)
                           : (MID_ + (mtbase + i) * 64 + (s - 64));
        vgb_s[tid] = vgb[src];
    }

    int mid0_0 = mtbase * 64, mid0_1 = (mtbase + 1) * 64;
    u32x4 wr[2], wr2[2];
    wstage_load(wr, wvg, mid0_0, 0, tid);   // (tile0, h0)
    __syncthreads();                         // bias ready (also wlds free)

    #pragma unroll
    for (int i = 0; i < 2; ++i) {
        int mid0 = (i == 0) ? mid0_0 : mid0_1;

        f32x4 accA[8];
        #pragma unroll
        for (int a = 0; a < 8; ++a) accA[a] = (f32x4){0.f, 0.f, 0.f, 0.f};

        // ---- half 0
        wstage_write(wr, wlds, tid);
        wstage_load(wr2, wvg, mid0, 1, tid);          // issue-early next half
        __syncthreads();                               // wlds(h0) ready
        vg_mfma_half(wlds, xwA, 0, l16, lg, accA);
        __syncthreads();                               // wlds(h0) consumed

        // ---- half 1
        wstage_write(wr2, wlds, tid);
        if (i == 0) wstage_load(wr, wvg, mid0_1, 0, tid);  // prefetch tile1 h0
        __syncthreads();                               // wlds(h1) ready
        vg_mfma_half(wlds, xwA, 1, l16, lg, accA);
        // (wlds reads protected by the vlds barriers below)

        // bias + sigmoid; v -> vlds (scalar row stores), gate -> registers
        unsigned gpack[4][2];
        int col = nb + l16;
        #pragma unroll
        for (int rt = 0; rt < 8; ++rt) {
            unsigned short sgb[4];
            #pragma unroll
            for (int r = 0; r < 4; ++r) {
                int s = rt * 16 + lg * 4 + r;
                float bias = vgb_s[i * 128 + s];
                float t = accA[rt][r] + bias;
                sgb[r] = f2bf(__builtin_amdgcn_rcpf(1.f + __expf(-t)));
            }
            if (rt < 4) {
                #pragma unroll
                for (int r = 0; r < 4; ++r)
                    vlds[rt * 16 + lg * 4 + r][col] = sgb[r];
            } else {
                gpack[rt - 4][0] = (unsigned)sgb[0] | ((unsigned)sgb[1] << 16);
                gpack[rt - 4][1] = (unsigned)sgb[2] | ((unsigned)sgb[3] << 16);
            }
        }
        __syncthreads();   // (1) vlds ready (and wlds h1 reads done)

        // ---- stage B: pv slab [64 mid][wave's 16 n] = v @ attn^T
        f32x4 acc2[4];
        #pragma unroll
        for (int a = 0; a < 4; ++a) acc2[a] = (f32x4){0.f, 0.f, 0.f, 0.f};
        #pragma unroll 2
        for (int kk = 0; kk < 8; ++kk) {
            int m0 = kk * 32 + lg * 8;
            frag8 b0 = loadf8(awA + m0);
            #pragma unroll
            for (int rt = 0; rt < 4; ++rt) {
                frag8 av = loadf8(&vlds[rt * 16 + l16][m0]);
                acc2[rt] = MFMA(av, b0, acc2[rt]);
            }
        }
        __syncthreads();   // (2) vlds consumed; next iter may overwrite

        // gate-multiply + plain store pvg[n][mid]
        int n = nb + l16;
        #pragma unroll
        for (int rt = 0; rt < 4; ++rt) {
            int midb = mid0 + rt * 16 + lg * 4;
            unsigned g01 = gpack[rt][0], g23 = gpack[rt][1];
            ushort4 t;
            t.x = f2bf(acc2[rt][0] * bf2f((unsigned short)(g01 & 0xffff)));
            t.y = f2bf(acc2[rt][1] * bf2f((unsigned short)(g01 >> 16)));
            t.z = f2bf(acc2[rt][2] * bf2f((unsigned short)(g23 & 0xffff)));
            t.w = f2bf(acc2[rt][3] * bf2f((unsigned short)(g23 >> 16)));
            *reinterpret_cast<ushort4*>(pw_out + (long)n * MID_ + midb) = t;
        }
    }
}

// ---------------- k_pconv: out = Wp @ pvg + bias (K=1024, wp via LDS) (R12) -----
__global__ __launch_bounds__(256, 4) void k_pconv(const unsigned short* __restrict__ pvg,
                                                  const unsigned short* __restrict__ wp,
                                                  const float* __restrict__ pb,
                                                  float* __restrict__ out) {
    __shared__ __align__(16) char wplds[32768];   // [256 rows][64 k] bf16, swizzled
    __shared__ float pbs[256];
    int bid = blockIdx.x;
    int win = bid >> 2, q = bid & 3;
    int tid = threadIdx.x, w = tid >> 6, l = tid & 63;
    int l16 = l & 15, lg = l >> 4;
    int nbase = q * 64 + w * 16;
    const unsigned short* bp = pvg + ((long)win * N_ + nbase) * MID_;
    const unsigned short* wrow = wp + (long)tid * MID_;   // thread stages out-row=tid

    pbs[tid] = pb[tid];

    f32x4 acc[16];
    #pragma unroll
    for (int c = 0; c < 16; ++c) acc[c] = (f32x4){0.f, 0.f, 0.f, 0.f};

    u32x4 wr[8];
    #pragma unroll
    for (int j = 0; j < 8; ++j)          // prefetch chunk 0 (row tid, k 0..63)
        wr[j] = *reinterpret_cast<const u32x4*>(wrow + j * 8);
    __syncthreads();                      // pbs ready

    int sw = (tid & 7) << 4;
    for (int c = 0; c < 16; ++c) {
        #pragma unroll
        for (int j = 0; j < 8; ++j)       // write staged chunk (swizzled slots)
            *reinterpret_cast<u32x4*>(wplds + tid * 128 + ((j * 16) ^ sw)) = wr[j];
        __syncthreads();                   // wplds ready
        if (c < 15) {
            #pragma unroll
            for (int j = 0; j < 8; ++j)   // issue-early next chunk (hides under MFMA)
                wr[j] = *reinterpret_cast<const u32x4*>(wrow + (c + 1) * 64 + j * 8);
        }
        #pragma unroll
        for (int kk2 = 0; kk2 < 2; ++kk2) {
            int k0 = c * 64 + kk2 * 32 + lg * 8;
            frag8 bf = loadf8(bp + l16 * MID_ + k0);
            int slot = (kk2 * 4 + lg) * 16;
            #pragma unroll
            for (int ct = 0; ct < 16; ++ct) {
                int row = ct * 16 + l16;
                frag8 af = *reinterpret_cast<const frag8*>(
                    wplds + row * 128 + (slot ^ ((row & 7) << 4)));
                acc[ct] = MFMA(af, bf, acc[ct]);
            }
        }
        __syncthreads();                   // wplds consumed
    }

    int b = win >> 6, wh = (win >> 3) & 7, ww = win & 7;
    int h = wh * 16 + q * 4 + w;
    int wc = ww * 16 + l16;
    #pragma unroll
    for (int ct = 0; ct < 16; ++ct) {
        #pragma unroll
        for (int r = 0; r < 4; ++r) {
            int cc = ct * 16 + lg * 4 + r;
            out[((long)(b * C_ + cc)) * (H_ * W_) + h * W_ + wc] = acc[ct][r] + pbs[cc];
        }
    }
}

// ---------------- fallback fused kernel (if ws too small for pvg) ----------------
__global__ __launch_bounds__(512, 2) void k_main(const unsigned short* __restrict__ xfT,
                                                 const unsigned short* __restrict__ attn,
                                                 const unsigned short* __restrict__ wvg,
                                                 const unsigned short* __restrict__ wp,
                                                 const float* __restrict__ vgb,
                                                 const float* __restrict__ pb,
                                                 float* __restrict__ out) {
    __shared__ __align__(16) unsigned short vlds[64][264];
    __shared__ __align__(16) unsigned short glds[64][264];
    __shared__ __align__(16) unsigned short pvgT[256][72];
    __shared__ float vgb_s[2048];
    __shared__ float pb_s[256];
    int wdw = blockIdx.x;
    int tid = threadIdx.x, w = tid >> 6, l = tid & 63;
    int l16 = l & 15, lg = l >> 4;
    int nb = 32 * w;
    const unsigned short* xw = xfT + (long)wdw * (N_ * C_);
    const unsigned short* aw = attn + (long)wdw * (N_ * N_);

    {
        float4 v = reinterpret_cast<const float4*>(vgb)[tid];
        reinterpret_cast<float4*>(vgb_s)[tid] = v;
        if (tid < 256) pb_s[tid] = pb[tid];
    }

    f32x4 acc3[16][2];
    #pragma unroll
    for (int a = 0; a < 16; ++a)
        #pragma unroll
        for (int c = 0; c < 2; ++c) acc3[a][c] = (f32x4){0.f, 0.f, 0.f, 0.f};

    __syncthreads();

    for (int mt = 0; mt < 16; ++mt) {
        int mid0 = mt * 64;
        f32x4 accA[8][2];
        #pragma unroll
        for (int a = 0; a < 8; ++a) {
            accA[a][0] = (f32x4){0.f, 0.f, 0.f, 0.f};
            accA[a][1] = (f32x4){0.f, 0.f, 0.f, 0.f};
        }
        for (int kk = 0; kk < 8; ++kk) {
            int c0 = kk * 32 + lg * 8;
            frag8 b0 = loadf8(xw + (nb + l16) * 256 + c0);
            frag8 b1 = loadf8(xw + (nb + 16 + l16) * 256 + c0);
            #pragma unroll
            for (int rt = 0; rt < 8; ++rt) {
                int s = rt * 16 + l16;
                int row = (rt < 4) ? (mid0 + s) : (MID_ + mid0 + s - 64);
                frag8 af = loadf8(wvg + row * 256 + c0);
                accA[rt][0] = MFMA(af, b0, accA[rt][0]);
                accA[rt][1] = MFMA(af, b1, accA[rt][1]);
            }
        }
        #pragma unroll
        for (int rt = 0; rt < 8; ++rt) {
            #pragma unroll
            for (int ct = 0; ct < 2; ++ct) {
                int col = nb + ct * 16 + l16;
                #pragma unroll
                for (int r = 0; r < 4; ++r) {
                    int s = rt * 16 + lg * 4 + r;
                    float bias = (rt < 4) ? vgb_s[mid0 + s] : vgb_s[MID_ + mid0 + s - 64];
                    float t = accA[rt][ct][r] + bias;
                    float sg = __builtin_amdgcn_rcpf(1.f + __expf(-t));
                    if (rt < 4) vlds[s][col] = f2bf(sg);
                    else        glds[s - 64][col] = f2bf(sg);
                }
            }
        }
        __syncthreads();

        f32x4 acc2[4][2];
        #pragma unroll
        for (int a = 0; a < 4; ++a) {
            acc2[a][0] = (f32x4){0.f, 0.f, 0.f, 0.f};
            acc2[a][1] = (f32x4){0.f, 0.f, 0.f, 0.f};
        }
        for (int kk = 0; kk < 8; ++kk) {
            int m0 = kk * 32 + lg * 8;
            frag8 b0 = loadf8(aw + (nb + l16) * 256 + m0);
            frag8 b1 = loadf8(aw + (nb + 16 + l16) * 256 + m0);
            #pragma unroll
            for (int rt = 0; rt < 4; ++rt) {
                frag8 av = loadf8(&vlds[rt * 16 + l16][m0]);
                acc2[rt][0] = MFMA(av, b0, acc2[rt][0]);
                acc2[rt][1] = MFMA(av, b1, acc2[rt][1]);
            }
        }
        {
            #pragma unroll
            for (int rt = 0; rt < 4; ++rt) {
                int midb = rt * 16 + lg * 4;
                #pragma unroll
                for (int ct = 0; ct < 2; ++ct) {
                    int n = nb + ct * 16 + l16;
                    ushort4 t;
                    t.x = f2bf(acc2[rt][ct][0] * bf2f(glds[midb + 0][n]));
                    t.y = f2bf(acc2[rt][ct][1] * bf2f(glds[midb + 1][n]));
                    t.z = f2bf(acc2[rt][ct][2] * bf2f(glds[midb + 2][n]));
                    t.w = f2bf(acc2[rt][ct][3] * bf2f(glds[midb + 3][n]));
                    *reinterpret_cast<ushort4*>(&pvgT[n][midb]) = t;
                }
            }
        }
        __syncthreads();

        #pragma unroll
        for (int kk2 = 0; kk2 < 2; ++kk2) {
            int k0 = kk2 * 32 + lg * 8;
            frag8 b0 = loadf8(&pvgT[nb + l16][k0]);
            frag8 b1 = loadf8(&pvgT[nb + 16 + l16][k0]);
            #pragma unroll
            for (int rt = 0; rt < 16; ++rt) {
                frag8 ap = loadf8(wp + (rt * 16 + l16) * 1024 + mid0 + k0);
                acc3[rt][0] = MFMA(ap, b0, acc3[rt][0]);
                acc3[rt][1] = MFMA(ap, b1, acc3[rt][1]);
            }
        }
    }

    int b = wdw >> 6, wh = (wdw >> 3) & 7, ww = wdw & 7;
    #pragma unroll
    for (int rt = 0; rt < 16; ++rt) {
        #pragma unroll
        for (int ct = 0; ct < 2; ++ct) {
            int h = wh * 16 + 2 * w + ct;
            int wc = ww * 16 + l16;
            #pragma unroll
            for (int r = 0; r < 4; ++r) {
                int c = rt * 16 + lg * 4 + r;
                out[(((long)(b * C_ + c)) * H_ + h) * W_ + wc] = acc3[rt][ct][r] + pb_s[c];
            }
        }
    }
}

extern "C" void kernel_launch(void* const* d_in, const int* in_sizes, int n_in,
                              void* d_out, int out_size, void* d_ws, size_t ws_size,
                              hipStream_t stream) {
    const float* x    = (const float*)d_in[0];
    const float* q_w  = (const float*)d_in[1];
    const float* q_s  = (const float*)d_in[2];
    const float* q_b  = (const float*)d_in[3];
    const float* k_w  = (const float*)d_in[4];
    const float* k_s  = (const float*)d_in[5];
    const float* k_b  = (const float*)d_in[6];
    const float* vg_w = (const float*)d_in[7];
    const float* vg_s = (const float*)d_in[8];
    const float* vg_b = (const float*)d_in[9];
    const float* p_w  = (const float*)d_in[10];
    const float* p_s  = (const float*)d_in[11];
    const float* p_b  = (const float*)d_in[12];

    // ws layout (bf16 as ushort)
    unsigned short* xfT  = (unsigned short*)d_ws;                    // 16,777,216
    unsigned short* attn = xfT + (size_t)NW_ * N_ * C_;              // 16,777,216
    unsigned short* wvg  = attn + (size_t)NW_ * N_ * N_;             // 524,288
    unsigned short* wqk  = wvg + 2048 * 256;                         // 32,768
    unsigned short* wp   = wqk + 128 * 256;                          // 262,144
    unsigned short* pvg  = wp + 256 * 1024;                          // 67,108,864
    size_t base_elems = (size_t)NW_ * N_ * C_ + (size_t)NW_ * N_ * N_ +
                        2048 * 256 + 128 * 256 + 256 * 1024;
    size_t need_fused = base_elems * sizeof(unsigned short);
    size_t need_split = (base_elems + (size_t)NW_ * N_ * MID_) * sizeof(unsigned short);
    if (ws_size < need_fused) return;

    k_wprep<<<3200, 256, 0, stream>>>(q_w, q_s, k_w, k_s, vg_w, vg_s, p_w, p_s,
                                      wvg, wqk, wp);
    k_pack<<<1024, 256, 0, stream>>>(x, xfT);
    k_attn<<<NW_ * 2, 512, 0, stream>>>(xfT, wqk, q_b, k_b, attn);
    if (ws_size >= need_split) {
        k_vgpv<<<NW_ * 8, 1024, 0, stream>>>(xfT, attn, wvg, vg_b, pvg);
        k_pconv<<<NW_ * 4, 256, 0, stream>>>(pvg, wp, p_b, (float*)d_out);
    } else {
        k_main<<<NW_, 512, 0, stream>>>(xfT, attn, wvg, wp, vg_b, p_b, (float*)d_out);
    }
}

// Round 21
// 353.576 us; speedup vs baseline: 1.0160x; 1.0160x over previous
//
#include <hip/hip_runtime.h>
#include <hip/hip_bf16.h>

#define B_    4
#define C_    256
#define H_    128
#define W_    128
#define NW_   256     // number of windows (B*8*8)
#define N_    256     // tokens per window
#define DA_   64
#define MID_  1024
#define SCALE_ 0.125f

typedef __attribute__((ext_vector_type(8))) __bf16 frag8;
typedef __attribute__((ext_vector_type(4))) float  f32x4;
typedef __attribute__((ext_vector_type(4))) unsigned int u32x4;

#define MFMA(a, b, c) __builtin_amdgcn_mfma_f32_16x16x32_bf16(a, b, c, 0, 0, 0)

__device__ __forceinline__ unsigned short f2bf(float x) {
    union { float f; unsigned u; } v; v.f = x;
    unsigned r = v.u + 0x7FFFu + ((v.u >> 16) & 1u);
    return (unsigned short)(r >> 16);
}
__device__ __forceinline__ float bf2f(unsigned short h) {
    union { unsigned u; float f; } v; v.u = ((unsigned)h) << 16;
    return v.f;
}
__device__ __forceinline__ frag8 loadf8(const unsigned short* p) {
    return *reinterpret_cast<const frag8*>(p);
}

// ---------------- weight prep: fold scales, cast to bf16 ----------------
__global__ void k_wprep(const float* __restrict__ qw, const float* __restrict__ qs,
                        const float* __restrict__ kw, const float* __restrict__ ks,
                        const float* __restrict__ vgw, const float* __restrict__ vgs,
                        const float* __restrict__ pw, const float* __restrict__ ps,
                        unsigned short* __restrict__ wvg,
                        unsigned short* __restrict__ wqk,
                        unsigned short* __restrict__ wp) {
    int i = blockIdx.x * 256 + threadIdx.x;
    if (i < 2048 * 256) {
        int r = i >> 8;
        wvg[i] = f2bf(vgw[i] * vgs[r]);
        return;
    }
    int j = i - 2048 * 256;
    if (j < 128 * 256) {
        int r = j >> 8, c = j & 255;
        float v = (r < 64) ? qw[r * 256 + c] * qs[r] * SCALE_
                           : kw[(r - 64) * 256 + c] * ks[r - 64];
        wqk[j] = f2bf(v);
        return;
    }
    int m = j - 128 * 256;
    if (m < 256 * 1024) {
        int o = m >> 10;
        wp[m] = f2bf(pw[m] * ps[o]);
    }
}

// ---------------- pack: x[B,C,H,W] -> xfT[win][n][c] bf16 ----------------
__global__ void k_pack(const float* __restrict__ x, unsigned short* __restrict__ xfT) {
    __shared__ unsigned short tile[64][258];
    int wdw = blockIdx.x >> 2, cq = blockIdx.x & 3;
    int b = wdw >> 6, wh = (wdw >> 3) & 7, ww = wdw & 7;
    int tid = threadIdx.x;
    int n = tid;
    int h = wh * 16 + (n >> 4), wc = ww * 16 + (n & 15);
    const float* xb = x + ((long)(b * C_ + cq * 64)) * (H_ * W_) + h * W_ + wc;
    #pragma unroll 4
    for (int cl = 0; cl < 64; ++cl)
        tile[cl][n] = f2bf(xb[cl * H_ * W_]);
    __syncthreads();
    unsigned short* dst = xfT + (long)wdw * (N_ * C_) + cq * 64;
    int cl = tid & 63;
    #pragma unroll 4
    for (int it = 0; it < 64; ++it) {
        int nn = it * 4 + (tid >> 6);
        dst[nn * C_ + cl] = tile[cl][nn];
    }
}

// ---------------- attention: q/k conv + softmax(q^T k) -> attn bf16 (R15) -------
__global__ __launch_bounds__(512, 4) void k_attn(const unsigned short* __restrict__ xfT,
                                                 const unsigned short* __restrict__ wqk,
                                                 const float* __restrict__ qb,
                                                 const float* __restrict__ kb,
                                                 unsigned short* __restrict__ attn) {
    __shared__ __align__(16) char smem[73728];
    unsigned short (*qT)[72] = reinterpret_cast<unsigned short(*)[72]>(smem);
    unsigned short (*kT)[72] = reinterpret_cast<unsigned short(*)[72]>(smem + 36864);
    char* wqlds = smem;   // [128 rows][256 c] bf16, swizzled; aliases qT/kT
    int wdw = blockIdx.x;
    int tid = threadIdx.x, w = tid >> 6, l = tid & 63;
    int l16 = l & 15, lg = l >> 4;
    const unsigned short* xw = xfT + (long)wdw * (N_ * C_);

    {   // cooperative stage wqk -> wqlds; physical byte = row*512 + (bc ^ ((row&7)<<4))
        int srow = tid >> 2;
        int cb = (tid & 3) * 128;
        const u32x4* src = reinterpret_cast<const u32x4*>(wqk + srow * 256 + (tid & 3) * 64);
        int sw = (srow & 7) << 4;
        #pragma unroll
        for (int j = 0; j < 8; ++j)
            *reinterpret_cast<u32x4*>(wqlds + srow * 512 + ((cb + j * 16) ^ sw)) = src[j];
    }
    __syncthreads();

    // stage 1: preact[128 rows][wave's 32 n]; A from LDS, B (xf) from global
    f32x4 acc[8][2];
    #pragma unroll
    for (int a = 0; a < 8; ++a) {
        acc[a][0] = (f32x4){0.f, 0.f, 0.f, 0.f};
        acc[a][1] = (f32x4){0.f, 0.f, 0.f, 0.f};
    }
    for (int kk = 0; kk < 8; ++kk) {
        int c0 = kk * 32 + lg * 8;
        frag8 b0 = loadf8(xw + (32 * w + l16) * 256 + c0);
        frag8 b1 = loadf8(xw + (32 * w + 16 + l16) * 256 + c0);
        int cbyte = c0 * 2;
        #pragma unroll
        for (int rt = 0; rt < 8; ++rt) {
            int row = rt * 16 + l16;
            frag8 af = *reinterpret_cast<const frag8*>(
                wqlds + row * 512 + (cbyte ^ ((row & 7) << 4)));
            acc[rt][0] = MFMA(af, b0, acc[rt][0]);
            acc[rt][1] = MFMA(af, b1, acc[rt][1]);
        }
    }
    __syncthreads();   // all wqlds reads done; qT/kT may now overwrite the region

    #pragma unroll
    for (int rt = 0; rt < 8; ++rt) {
        int rowb = rt * 16 + lg * 4;
        bool isq = rt < 4;
        float b0 = isq ? qb[rowb + 0] * SCALE_ : kb[rowb - 64 + 0];
        float b1 = isq ? qb[rowb + 1] * SCALE_ : kb[rowb - 64 + 1];
        float b2 = isq ? qb[rowb + 2] * SCALE_ : kb[rowb - 64 + 2];
        float b3 = isq ? qb[rowb + 3] * SCALE_ : kb[rowb - 64 + 3];
        #pragma unroll
        for (int ct = 0; ct < 2; ++ct) {
            int col = 32 * w + ct * 16 + l16;
            ushort4 t;
            t.x = f2bf(acc[rt][ct][0] + b0);
            t.y = f2bf(acc[rt][ct][1] + b1);
            t.z = f2bf(acc[rt][ct][2] + b2);
            t.w = f2bf(acc[rt][ct][3] + b3);
            unsigned short* dstp = isq ? &qT[col][rowb] : &kT[col][rowb - 64];
            *reinterpret_cast<ushort4*>(dstp) = t;
        }
    }
    __syncthreads();   // qT/kT ready

    #pragma unroll
    for (int pass = 0; pass < 2; ++pass) {
        int n0 = pass * 128 + w * 16;
        f32x4 a2[16];
        #pragma unroll
        for (int c = 0; c < 16; ++c) a2[c] = (f32x4){0.f, 0.f, 0.f, 0.f};
        #pragma unroll
        for (int kk = 0; kk < 2; ++kk) {
            int k0 = kk * 32 + lg * 8;
            frag8 af = loadf8(&qT[n0 + l16][k0]);
            #pragma unroll
            for (int ct = 0; ct < 16; ++ct) {
                frag8 bf = loadf8(&kT[ct * 16 + l16][k0]);
                a2[ct] = MFMA(af, bf, a2[ct]);
            }
        }
        #pragma unroll
        for (int r = 0; r < 4; ++r) {
            int n = n0 + lg * 4 + r;
            float mx = -1e30f;
            #pragma unroll
            for (int ct = 0; ct < 16; ++ct) mx = fmaxf(mx, a2[ct][r]);
            #pragma unroll
            for (int d = 1; d < 16; d <<= 1) mx = fmaxf(mx, __shfl_xor(mx, d, 64));
            float p[16], s = 0.f;
            #pragma unroll
            for (int ct = 0; ct < 16; ++ct) { p[ct] = __expf(a2[ct][r] - mx); s += p[ct]; }
            #pragma unroll
            for (int d = 1; d < 16; d <<= 1) s += __shfl_xor(s, d, 64);
            float inv = __builtin_amdgcn_rcpf(s);
            unsigned short* dst = attn + (long)wdw * (N_ * N_) + n * 256 + l16;
            #pragma unroll
            for (int ct = 0; ct < 16; ++ct) dst[ct * 16] = f2bf(p[ct] * inv);
        }
    }
}

// ============== k_vgpv weight-staging helpers (1024-thread variant) ==============
// wlds: linear 32 KB = half weight slab [128 rows][128 c] bf16.
// XOR swizzle: physical_byte(row, bc) = row*256 + (bc ^ ((row&7)<<4)).
// 1024 threads: 8 threads/row x 32 B each.
__device__ __forceinline__ void wstage_load(u32x4 wr[2], const unsigned short* __restrict__ wvg,
                                            int mid0, int h, int tid) {
    int srow = tid >> 3;            // 0..127
    long grow = (srow < 64) ? (long)(mid0 + srow) : (long)(MID_ + mid0 + srow - 64);
    const u32x4* src = reinterpret_cast<const u32x4*>(wvg + grow * 256 + h * 128 + (tid & 7) * 16);
    wr[0] = src[0];
    wr[1] = src[1];
}
__device__ __forceinline__ void wstage_write(const u32x4 wr[2], char* wlds, int tid) {
    int srow = tid >> 3;
    int cb = (tid & 7) * 32;
    int sw = (srow & 7) << 4;
    *reinterpret_cast<u32x4*>(wlds + srow * 256 + (cb ^ sw)) = wr[0];
    *reinterpret_cast<u32x4*>(wlds + srow * 256 + ((cb + 16) ^ sw)) = wr[1];
}
// one c-half of stage A: 4 kk steps, A from LDS (swizzled), B (xf) from global.
// Wave owns 16 n-cols -> single B-frag per kk.
__device__ __forceinline__ void vg_mfma_half(const char* wlds,
                                             const unsigned short* __restrict__ xwA,
                                             int h, int l16, int lg, f32x4 accA[8]) {
    #pragma unroll
    for (int kkl = 0; kkl < 4; ++kkl) {
        int c0 = h * 128 + kkl * 32 + lg * 8;
        frag8 b0 = loadf8(xwA + c0);
        int cbase = kkl * 64 + lg * 16;
        #pragma unroll
        for (int rt = 0; rt < 8; ++rt) {
            int row = rt * 16 + l16;
            frag8 af = *reinterpret_cast<const frag8*>(
                wlds + row * 256 + (cbase ^ ((row & 7) << 4)));
            accA[rt] = MFMA(af, b0, accA[rt]);
        }
    }
}

// ---------------- k_vgpv: vg conv + sigmoid -> PV -> gate -> pvg (global) -------
// R16 exact (best measured passing config: ~220 us).
__global__ __launch_bounds__(1024, 4) void k_vgpv(const unsigned short* __restrict__ xfT,
                                                  const unsigned short* __restrict__ attn,
                                                  const unsigned short* __restrict__ wvg,
                                                  const float* __restrict__ vgb,
                                                  unsigned short* __restrict__ pvg) {
    __shared__ __align__(16) unsigned short vlds[64][264];
    __shared__ __align__(16) char wlds[32768];
    __shared__ float vgb_s[256];     // 2 tiles x (64 v-bias, 64 g-bias)
    int bid = blockIdx.x;
    int lane8 = bid & 7, rr = bid >> 3;
    int sub = rr & 7, winHi = rr >> 3;
    int wdw = winHi * 8 + lane8;
    int mtbase = sub * 2;

    int tid = threadIdx.x, w = tid >> 6, l = tid & 63;   // w: 0..15
    int l16 = l & 15, lg = l >> 4;
    int nb = 16 * w;                                     // wave's 16 n-cols
    const unsigned short* xw = xfT + (long)wdw * (N_ * C_);
    const unsigned short* xwA = xw + (nb + l16) * 256;
    const unsigned short* aw = attn + (long)wdw * (N_ * N_);
    const unsigned short* awA = aw + (nb + l16) * 256;
    unsigned short* pw_out = pvg + (long)wdw * (N_ * MID_);

    if (tid < 256) {   // bias slice: [i*128 + s], s<64 => v, s>=64 => gate
        int i = tid >> 7, s = tid & 127;
        int src = (s < 64) ? ((mtbase + i) * 64 + s)
                           : (MID_ + (mtbase + i) * 64 + (s - 64));
        vgb_s[tid] = vgb[src];
    }

    int mid0_0 = mtbase * 64, mid0_1 = (mtbase + 1) * 64;
    u32x4 wr[2], wr2[2];
    wstage_load(wr, wvg, mid0_0, 0, tid);   // (tile0, h0)
    __syncthreads();                         // bias ready (also wlds free)

    #pragma unroll
    for (int i = 0; i < 2; ++i) {
        int mid0 = (i == 0) ? mid0_0 : mid0_1;

        f32x4 accA[8];
        #pragma unroll
        for (int a = 0; a < 8; ++a) accA[a] = (f32x4){0.f, 0.f, 0.f, 0.f};

        // ---- half 0
        wstage_write(wr, wlds, tid);
        wstage_load(wr2, wvg, mid0, 1, tid);          // issue-early next half
        __syncthreads();                               // wlds(h0) ready
        vg_mfma_half(wlds, xwA, 0, l16, lg, accA);
        __syncthreads();                               // wlds(h0) consumed

        // ---- half 1
        wstage_write(wr2, wlds, tid);
        if (i == 0) wstage_load(wr, wvg, mid0_1, 0, tid);  // prefetch tile1 h0
        __syncthreads();                               // wlds(h1) ready
        vg_mfma_half(wlds, xwA, 1, l16, lg, accA);
        // (wlds reads protected by the vlds barriers below)

        // bias + sigmoid; v -> vlds (scalar row stores), gate -> registers
        unsigned gpack[4][2];
        int col = nb + l16;
        #pragma unroll
        for (int rt = 0; rt < 8; ++rt) {
            unsigned short sgb[4];
            #pragma unroll
            for (int r = 0; r < 4; ++r) {
                int s = rt * 16 + lg * 4 + r;
                float bias = vgb_s[i * 128 + s];
                float t = accA[rt][r] + bias;
                sgb[r] = f2bf(__builtin_amdgcn_rcpf(1.f + __expf(-t)));
            }
            if (rt < 4) {
                #pragma unroll
                for (int r = 0; r < 4; ++r)
                    vlds[rt * 16 + lg * 4 + r][col] = sgb[r];
            } else {
                gpack[rt - 4][0] = (unsigned)sgb[0] | ((unsigned)sgb[1] << 16);
                gpack[rt - 4][1] = (unsigned)sgb[2] | ((unsigned)sgb[3] << 16);
            }
        }
        __syncthreads();   // (1) vlds ready (and wlds h1 reads done)

        // ---- stage B: pv slab [64 mid][wave's 16 n] = v @ attn^T
        f32x4 acc2[4];
        #pragma unroll
        for (int a = 0; a < 4; ++a) acc2[a] = (f32x4){0.f, 0.f, 0.f, 0.f};
        #pragma unroll 2
        for (int kk = 0; kk < 8; ++kk) {
            int m0 = kk * 32 + lg * 8;
            frag8 b0 = loadf8(awA + m0);
            #pragma unroll
            for (int rt = 0; rt < 4; ++rt) {
                frag8 av = loadf8(&vlds[rt * 16 + l16][m0]);
                acc2[rt] = MFMA(av, b0, acc2[rt]);
            }
        }
        __syncthreads();   // (2) vlds consumed; next iter may overwrite

        // gate-multiply + plain store pvg[n][mid]
        int n = nb + l16;
        #pragma unroll
        for (int rt = 0; rt < 4; ++rt) {
            int midb = mid0 + rt * 16 + lg * 4;
            unsigned g01 = gpack[rt][0], g23 = gpack[rt][1];
            ushort4 t;
            t.x = f2bf(acc2[rt][0] * bf2f((unsigned short)(g01 & 0xffff)));
            t.y = f2bf(acc2[rt][1] * bf2f((unsigned short)(g01 >> 16)));
            t.z = f2bf(acc2[rt][2] * bf2f((unsigned short)(g23 & 0xffff)));
            t.w = f2bf(acc2[rt][3] * bf2f((unsigned short)(g23 >> 16)));
            *reinterpret_cast<ushort4*>(pw_out + (long)n * MID_ + midb) = t;
        }
    }
}

// ---------------- k_pconv: out = Wp @ pvg + bias (K=1024, wp via LDS) (R12) -----
__global__ __launch_bounds__(256, 4) void k_pconv(const unsigned short* __restrict__ pvg,
                                                  const unsigned short* __restrict__ wp,
                                                  const float* __restrict__ pb,
                                                  float* __restrict__ out) {
    __shared__ __align__(16) char wplds[32768];   // [256 rows][64 k] bf16, swizzled
    __shared__ float pbs[256];
    int bid = blockIdx.x;
    int win = bid >> 2, q = bid & 3;
    int tid = threadIdx.x, w = tid >> 6, l = tid & 63;
    int l16 = l & 15, lg = l >> 4;
    int nbase = q * 64 + w * 16;
    const unsigned short* bp = pvg + ((long)win * N_ + nbase) * MID_;
    const unsigned short* wrow = wp + (long)tid * MID_;   // thread stages out-row=tid

    pbs[tid] = pb[tid];

    f32x4 acc[16];
    #pragma unroll
    for (int c = 0; c < 16; ++c) acc[c] = (f32x4){0.f, 0.f, 0.f, 0.f};

    u32x4 wr[8];
    #pragma unroll
    for (int j = 0; j < 8; ++j)          // prefetch chunk 0 (row tid, k 0..63)
        wr[j] = *reinterpret_cast<const u32x4*>(wrow + j * 8);
    __syncthreads();                      // pbs ready

    int sw = (tid & 7) << 4;
    for (int c = 0; c < 16; ++c) {
        #pragma unroll
        for (int j = 0; j < 8; ++j)       // write staged chunk (swizzled slots)
            *reinterpret_cast<u32x4*>(wplds + tid * 128 + ((j * 16) ^ sw)) = wr[j];
        __syncthreads();                   // wplds ready
        if (c < 15) {
            #pragma unroll
            for (int j = 0; j < 8; ++j)   // issue-early next chunk (hides under MFMA)
                wr[j] = *reinterpret_cast<const u32x4*>(wrow + (c + 1) * 64 + j * 8);
        }
        #pragma unroll
        for (int kk2 = 0; kk2 < 2; ++kk2) {
            int k0 = c * 64 + kk2 * 32 + lg * 8;
            frag8 bf = loadf8(bp + l16 * MID_ + k0);
            int slot = (kk2 * 4 + lg) * 16;
            #pragma unroll
            for (int ct = 0; ct < 16; ++ct) {
                int row = ct * 16 + l16;
                frag8 af = *reinterpret_cast<const frag8*>(
                    wplds + row * 128 + (slot ^ ((row & 7) << 4)));
                acc[ct] = MFMA(af, bf, acc[ct]);
            }
        }
        __syncthreads();                   // wplds consumed
    }

    int b = win >> 6, wh = (win >> 3) & 7, ww = win & 7;
    int h = wh * 16 + q * 4 + w;
    int wc = ww * 16 + l16;
    #pragma unroll
    for (int ct = 0; ct < 16; ++ct) {
        #pragma unroll
        for (int r = 0; r < 4; ++r) {
            int cc = ct * 16 + lg * 4 + r;
            out[((long)(b * C_ + cc)) * (H_ * W_) + h * W_ + wc] = acc[ct][r] + pbs[cc];
        }
    }
}

// ---------------- fallback fused kernel (if ws too small for pvg) ----------------
__global__ __launch_bounds__(512, 2) void k_main(const unsigned short* __restrict__ xfT,
                                                 const unsigned short* __restrict__ attn,
                                                 const unsigned short* __restrict__ wvg,
                                                 const unsigned short* __restrict__ wp,
                                                 const float* __restrict__ vgb,
                                                 const float* __restrict__ pb,
                                                 float* __restrict__ out) {
    __shared__ __align__(16) unsigned short vlds[64][264];
    __shared__ __align__(16) unsigned short glds[64][264];
    __shared__ __align__(16) unsigned short pvgT[256][72];
    __shared__ float vgb_s[2048];
    __shared__ float pb_s[256];
    int wdw = blockIdx.x;
    int tid = threadIdx.x, w = tid >> 6, l = tid & 63;
    int l16 = l & 15, lg = l >> 4;
    int nb = 32 * w;
    const unsigned short* xw = xfT + (long)wdw * (N_ * C_);
    const unsigned short* aw = attn + (long)wdw * (N_ * N_);

    {
        float4 v = reinterpret_cast<const float4*>(vgb)[tid];
        reinterpret_cast<float4*>(vgb_s)[tid] = v;
        if (tid < 256) pb_s[tid] = pb[tid];
    }

    f32x4 acc3[16][2];
    #pragma unroll
    for (int a = 0; a < 16; ++a)
        #pragma unroll
        for (int c = 0; c < 2; ++c) acc3[a][c] = (f32x4){0.f, 0.f, 0.f, 0.f};

    __syncthreads();

    for (int mt = 0; mt < 16; ++mt) {
        int mid0 = mt * 64;
        f32x4 accA[8][2];
        #pragma unroll
        for (int a = 0; a < 8; ++a) {
            accA[a][0] = (f32x4){0.f, 0.f, 0.f, 0.f};
            accA[a][1] = (f32x4){0.f, 0.f, 0.f, 0.f};
        }
        for (int kk = 0; kk < 8; ++kk) {
            int c0 = kk * 32 + lg * 8;
            frag8 b0 = loadf8(xw + (nb + l16) * 256 + c0);
            frag8 b1 = loadf8(xw + (nb + 16 + l16) * 256 + c0);
            #pragma unroll
            for (int rt = 0; rt < 8; ++rt) {
                int s = rt * 16 + l16;
                int row = (rt < 4) ? (mid0 + s) : (MID_ + mid0 + s - 64);
                frag8 af = loadf8(wvg + row * 256 + c0);
                accA[rt][0] = MFMA(af, b0, accA[rt][0]);
                accA[rt][1] = MFMA(af, b1, accA[rt][1]);
            }
        }
        #pragma unroll
        for (int rt = 0; rt < 8; ++rt) {
            #pragma unroll
            for (int ct = 0; ct < 2; ++ct) {
                int col = nb + ct * 16 + l16;
                #pragma unroll
                for (int r = 0; r < 4; ++r) {
                    int s = rt * 16 + lg * 4 + r;
                    float bias = (rt < 4) ? vgb_s[mid0 + s] : vgb_s[MID_ + mid0 + s - 64];
                    float t = accA[rt][ct][r] + bias;
                    float sg = __builtin_amdgcn_rcpf(1.f + __expf(-t));
                    if (rt < 4) vlds[s][col] = f2bf(sg);
                    else        glds[s - 64][col] = f2bf(sg);
                }
            }
        }
        __syncthreads();

        f32x4 acc2[4][2];
        #pragma unroll
        for (int a = 0; a < 4; ++a) {
            acc2[a][0] = (f32x4){0.f, 0.f, 0.f, 0.f};
            acc2[a][1] = (f32x4){0.f, 0.f, 0.f, 0.f};
        }
        for (int kk = 0; kk < 8; ++kk) {
            int m0 = kk * 32 + lg * 8;
            frag8 b0 = loadf8(aw + (nb + l16) * 256 + m0);
            frag8 b1 = loadf8(aw + (nb + 16 + l16) * 256 + m0);
            #pragma unroll
            for (int rt = 0; rt < 4; ++rt) {
                frag8 av = loadf8(&vlds[rt * 16 + l16][m0]);
                acc2[rt][0] = MFMA(av, b0, acc2[rt][0]);
                acc2[rt][1] = MFMA(av, b1, acc2[rt][1]);
            }
        }
        {
            #pragma unroll
            for (int rt = 0; rt < 4; ++rt) {
                int midb = rt * 16 + lg * 4;
                #pragma unroll
                for (int ct = 0; ct < 2; ++ct) {
                    int n = nb + ct * 16 + l16;
                    ushort4 t;
                    t.x = f2bf(acc2[rt][ct][0] * bf2f(glds[midb + 0][n]));
                    t.y = f2bf(acc2[rt][ct][1] * bf2f(glds[midb + 1][n]));
                    t.z = f2bf(acc2[rt][ct][2] * bf2f(glds[midb + 2][n]));
                    t.w = f2bf(acc2[rt][ct][3] * bf2f(glds[midb + 3][n]));
                    *reinterpret_cast<ushort4*>(&pvgT[n][midb]) = t;
                }
            }
        }
        __syncthreads();

        #pragma unroll
        for (int kk2 = 0; kk2 < 2; ++kk2) {
            int k0 = kk2 * 32 + lg * 8;
            frag8 b0 = loadf8(&pvgT[nb + l16][k0]);
            frag8 b1 = loadf8(&pvgT[nb + 16 + l16][k0]);
            #pragma unroll
            for (int rt = 0; rt < 16; ++rt) {
                frag8 ap = loadf8(wp + (rt * 16 + l16) * 1024 + mid0 + k0);
                acc3[rt][0] = MFMA(ap, b0, acc3[rt][0]);
                acc3[rt][1] = MFMA(ap, b1, acc3[rt][1]);
            }
        }
    }

    int b = wdw >> 6, wh = (wdw >> 3) & 7, ww = wdw & 7;
    #pragma unroll
    for (int rt = 0; rt < 16; ++rt) {
        #pragma unroll
        for (int ct = 0; ct < 2; ++ct) {
            int h = wh * 16 + 2 * w + ct;
            int wc = ww * 16 + l16;
            #pragma unroll
            for (int r = 0; r < 4; ++r) {
                int c = rt * 16 + lg * 4 + r;
                out[(((long)(b * C_ + c)) * H_ + h) * W_ + wc] = acc3[rt][ct][r] + pb_s[c];
            }
        }
    }
}

extern "C" void kernel_launch(void* const* d_in, const int* in_sizes, int n_in,
                              void* d_out, int out_size, void* d_ws, size_t ws_size,
                              hipStream_t stream) {
    const float* x    = (const float*)d_in[0];
    const float* q_w  = (const float*)d_in[1];
    const float* q_s  = (const float*)d_in[2];
    const float* q_b  = (const float*)d_in[3];
    const float* k_w  = (const float*)d_in[4];
    const float* k_s  = (const float*)d_in[5];
    const float* k_b  = (const float*)d_in[6];
    const float* vg_w = (const float*)d_in[7];
    const float* vg_s = (const float*)d_in[8];
    const float* vg_b = (const float*)d_in[9];
    const float* p_w  = (const float*)d_in[10];
    const float* p_s  = (const float*)d_in[11];
    const float* p_b  = (const float*)d_in[12];

    // ws layout (bf16 as ushort)
    unsigned short* xfT  = (unsigned short*)d_ws;                    // 16,777,216
    unsigned short* attn = xfT + (size_t)NW_ * N_ * C_;              // 16,777,216
    unsigned short* wvg  = attn + (size_t)NW_ * N_ * N_;             // 524,288
    unsigned short* wqk  = wvg + 2048 * 256;                         // 32,768
    unsigned short* wp   = wqk + 128 * 256;                          // 262,144
    unsigned short* pvg  = wp + 256 * 1024;                          // 67,108,864
    size_t base_elems = (size_t)NW_ * N_ * C_ + (size_t)NW_ * N_ * N_ +
                        2048 * 256 + 128 * 256 + 256 * 1024;
    size_t need_fused = base_elems * sizeof(unsigned short);
    size_t need_split = (base_elems + (size_t)NW_ * N_ * MID_) * sizeof(unsigned short);
    if (ws_size < need_fused) return;

    k_wprep<<<3200, 256, 0, stream>>>(q_w, q_s, k_w, k_s, vg_w, vg_s, p_w, p_s,
                                      wvg, wqk, wp);
    k_pack<<<1024, 256, 0, stream>>>(x, xfT);
    k_attn<<<NW_, 512, 0, stream>>>(xfT, wqk, q_b, k_b, attn);
    if (ws_size >= need_split) {
        k_vgpv<<<NW_ * 8, 1024, 0, stream>>>(xfT, attn, wvg, vg_b, pvg);
        k_pconv<<<NW_ * 4, 256, 0, stream>>>(pvg, wp, p_b, (float*)d_out);
    } else {
        k_main<<<NW_, 512, 0, stream>>>(xfT, attn, wvg, wp, vg_b, p_b, (float*)d_out);
    }
}